// Round 1
// baseline (6120.507 us; speedup 1.0000x reference)
//
#include <hip/hip_runtime.h>
#include <math.h>

// Problem constants
#define BATCH 512
#define TM1   31
#define DIMD  256
#define HE    512
#define HD    512

__device__ __forceinline__ float sigmf(float x) { return 1.f / (1.f + __expf(-x)); }

__device__ __forceinline__ float tanh_fast(float x) {
    float ax = fabsf(x);
    float t  = __expf(-2.f * ax);
    float r  = (1.f - t) / (1.f + t);
    return copysignf(r, x);
}

__device__ __forceinline__ float blockReduceSum256(float v, float* sred) {
#pragma unroll
    for (int m = 32; m > 0; m >>= 1) v += __shfl_xor(v, m);
    __syncthreads();
    if ((threadIdx.x & 63) == 0) sred[threadIdx.x >> 6] = v;
    __syncthreads();
    return sred[0] + sred[1] + sred[2] + sred[3];
}

__device__ __forceinline__ float blockReduceMax256(float v, float* sred) {
#pragma unroll
    for (int m = 32; m > 0; m >>= 1) v = fmaxf(v, __shfl_xor(v, m));
    __syncthreads();
    if ((threadIdx.x & 63) == 0) sred[threadIdx.x >> 6] = v;
    __syncthreads();
    return fmaxf(fmaxf(sred[0], sred[1]), fmaxf(sred[2], sred[3]));
}

// ---------------------------------------------------------------------------
// prep: build enc combined weights [Wih|Whh] (2048x768), combined biases,
// dec bias vector [zeros(512) | bih+bhh(2048)], and zero hc_dec.
// ---------------------------------------------------------------------------
__global__ __launch_bounds__(256) void prep_kernel(
    const float* __restrict__ eWih, const float* __restrict__ eWhh,
    const float* __restrict__ ebih, const float* __restrict__ ebhh,
    const float* __restrict__ dbih, const float* __restrict__ dbhh,
    float* __restrict__ eWcomb, float* __restrict__ ebcomb,
    float* __restrict__ dbias, float* __restrict__ hc_dec) {
    int idx = blockIdx.x * blockDim.x + threadIdx.x;
    int stride = gridDim.x * blockDim.x;
    for (int i = idx; i < 2048 * 768; i += stride) {
        int n = i / 768, k = i - n * 768;
        eWcomb[i] = (k < 256) ? eWih[n * 256 + k] : eWhh[n * 512 + (k - 256)];
    }
    for (int i = idx; i < 2048; i += stride) ebcomb[i] = ebih[i] + ebhh[i];
    for (int i = idx; i < 2560; i += stride)
        dbias[i] = (i < 512) ? 0.f : (dbih[i - 512] + dbhh[i - 512]);
    for (int i = idx; i < BATCH * 1024; i += stride) hc_dec[i] = 0.f;
}

// ---------------------------------------------------------------------------
// t2s: t2s[b][s][d] = sum_t X[b,t,d]*Wd[s,t] + bd[s]   (layout (B,31,256))
// ---------------------------------------------------------------------------
__global__ __launch_bounds__(256) void t2s_kernel(
    const float* __restrict__ inputs, const float* __restrict__ Wd,
    const float* __restrict__ bd, float* __restrict__ t2s) {
    __shared__ float sX[TM1 * DIMD];
    __shared__ float sWd[TM1 * TM1];
    int b = blockIdx.x, tid = threadIdx.x;
    for (int i = tid; i < TM1 * DIMD; i += 256) {
        int tt = i >> 8, d = i & 255;
        sX[i] = inputs[(b * TM1 + tt) * 257 + 1 + d];
    }
    for (int i = tid; i < TM1 * TM1; i += 256) sWd[i] = Wd[i];
    __syncthreads();
    int d = tid;
    for (int s = 0; s < TM1; s++) {
        float acc = bd[s];
        for (int tt = 0; tt < TM1; tt++) acc += sX[tt * DIMD + d] * sWd[s * TM1 + tt];
        t2s[(b * TM1 + s) * DIMD + d] = acc;
    }
}

// ---------------------------------------------------------------------------
// SGEMM: C[m,n] = sum_k A[m,k] * W[n,k] + bias[n]
// 64x64 tile, 256 threads, 4x4 per thread, BK=16, k-major LDS (stride 68).
// M,N divisible by 64; K divisible by 16.
// ---------------------------------------------------------------------------
__global__ __launch_bounds__(256) void gemm_tn(
    const float* __restrict__ A, int lda,
    const float* __restrict__ W, int ldw,
    const float* __restrict__ bias,
    float* __restrict__ C, int ldc, int K) {
    __shared__ float As[16][68];
    __shared__ float Ws[16][68];
    int tid = threadIdx.x;
    int n0 = blockIdx.x * 64;
    int m0 = blockIdx.y * 64;
    int lr = tid >> 2;            // 0..63 : row within tile
    int lc = (tid & 3) << 2;      // 0,4,8,12 : k offset
    int tx = tid & 15, ty = tid >> 4;
    float acc[4][4] = {};
    const float* Abase = A + (m0 + lr) * lda + lc;
    const float* Wbase = W + (n0 + lr) * ldw + lc;
    for (int k0 = 0; k0 < K; k0 += 16) {
        float4 av = *(const float4*)(Abase + k0);
        float4 wv = *(const float4*)(Wbase + k0);
        __syncthreads();
        As[lc + 0][lr] = av.x; As[lc + 1][lr] = av.y;
        As[lc + 2][lr] = av.z; As[lc + 3][lr] = av.w;
        Ws[lc + 0][lr] = wv.x; Ws[lc + 1][lr] = wv.y;
        Ws[lc + 2][lr] = wv.z; Ws[lc + 3][lr] = wv.w;
        __syncthreads();
#pragma unroll
        for (int k = 0; k < 16; k++) {
            float4 a = *(const float4*)(&As[k][ty * 4]);
            float4 b = *(const float4*)(&Ws[k][tx * 4]);
            acc[0][0] += a.x * b.x; acc[0][1] += a.x * b.y; acc[0][2] += a.x * b.z; acc[0][3] += a.x * b.w;
            acc[1][0] += a.y * b.x; acc[1][1] += a.y * b.y; acc[1][2] += a.y * b.z; acc[1][3] += a.y * b.w;
            acc[2][0] += a.z * b.x; acc[2][1] += a.z * b.y; acc[2][2] += a.z * b.z; acc[2][3] += a.z * b.w;
            acc[3][0] += a.w * b.x; acc[3][1] += a.w * b.y; acc[3][2] += a.w * b.z; acc[3][3] += a.w * b.w;
        }
    }
    float4 bv = *(const float4*)(bias + n0 + tx * 4);
#pragma unroll
    for (int i = 0; i < 4; i++) {
        int m = m0 + ty * 4 + i;
        float4 cv;
        cv.x = acc[i][0] + bv.x; cv.y = acc[i][1] + bv.y;
        cv.z = acc[i][2] + bv.z; cv.w = acc[i][3] + bv.w;
        *(float4*)(C + m * ldc + n0 + tx * 4) = cv;
    }
}

// ---------------------------------------------------------------------------
// Encoder step (grid=512 blocks, one per batch; 256 threads):
//  phase0: finalize LSTM of step t-1 from g (t>0); t==0 zero-init; t==31 only phase0
//  phase1: t1 -> score -> softmax -> w ; writes A_enc = [w | h]
// ---------------------------------------------------------------------------
__global__ __launch_bounds__(256) void enc_step_kernel(
    const float* __restrict__ inputs, const float* __restrict__ t2s,
    const float* __restrict__ Wc, const float* __restrict__ bc,
    const float* __restrict__ Wa, const float* __restrict__ ba,
    const float* __restrict__ g, float* __restrict__ hc,
    float* __restrict__ A_enc, float* __restrict__ enc_out, int t) {
    __shared__ float sh_hc[1024];
    __shared__ float t1s[TM1];
    __shared__ float sred[4];
    int b = blockIdx.x, tid = threadIdx.x;
    if (t > 0) {
        for (int e = tid; e < 512; e += 256) {
            float gi = g[b * 2048 + e];
            float gf = g[b * 2048 + 512 + e];
            float gg = g[b * 2048 + 1024 + e];
            float go = g[b * 2048 + 1536 + e];
            float cp = hc[b * 1024 + 512 + e];
            float c2 = sigmf(gf) * cp + sigmf(gi) * tanh_fast(gg);
            float h2 = sigmf(go) * tanh_fast(c2);
            hc[b * 1024 + e] = h2;
            hc[b * 1024 + 512 + e] = c2;
            sh_hc[e] = h2;
            sh_hc[512 + e] = c2;
            enc_out[(b * TM1 + (t - 1)) * 512 + e] = h2;
        }
    } else {
        for (int j = tid; j < 1024; j += 256) { sh_hc[j] = 0.f; hc[b * 1024 + j] = 0.f; }
    }
    __syncthreads();
    if (t == TM1) return;  // final call: only the LSTM finalize

    // t1[s] = [h|c] . Wc[s,:] + bc[s]   (8 lanes per s)
    if (tid < 248) {
        int s = tid >> 3, l8 = tid & 7;
        const float* wrow = Wc + s * 1024;
        float p = 0.f;
        for (int j = l8; j < 1024; j += 8) p += sh_hc[j] * wrow[j];
        p += __shfl_xor(p, 1); p += __shfl_xor(p, 2); p += __shfl_xor(p, 4);
        if (l8 == 0) t1s[s] = p + bc[s];
    }
    __syncthreads();

    // score[d] + softmax over d (one thread per d)
    int d = tid;
    float sc = ba[0];
    const float* t2p = t2s + b * TM1 * DIMD + d;
    for (int s = 0; s < TM1; s++) sc += tanh_fast(t1s[s] + t2p[s * DIMD]) * Wa[s];
    float mx = blockReduceMax256(sc, sred);
    float ex = __expf(sc - mx);
    float sm = blockReduceSum256(ex, sred);
    float w = (ex / sm) * inputs[(b * TM1 + t) * 257 + 1 + d];
    A_enc[b * 768 + d] = w;
    for (int j = tid; j < 512; j += 256) A_enc[b * 768 + 256 + j] = sh_hc[j];
}

// ---------------------------------------------------------------------------
// Decoder step (grid=512 blocks; 256 threads):
//  score[t'] = sum_e tanh(u[e]+V[b,t',e])*W2[e] + b2 ; softmax; ctx; y_tilde;
//  LSTM pointwise using gh (= h@Whh^T + biases) + y_tilde*Wih.
// ---------------------------------------------------------------------------
__global__ __launch_bounds__(256) void dec_step_kernel(
    const float* __restrict__ inputs, const float* __restrict__ V,
    const float* __restrict__ W2, const float* __restrict__ b2,
    const float* __restrict__ enc_out, const float* __restrict__ fcW,
    const float* __restrict__ fcb, const float* __restrict__ Wih,
    const float* __restrict__ gu, float* __restrict__ hc,
    float* __restrict__ ctx, int t) {
    __shared__ float su[512];
    __shared__ float sw2[512];
    __shared__ float s_att[TM1];
    __shared__ float sred[4];
    int b = blockIdx.x, tid = threadIdx.x;
    for (int e = tid; e < 512; e += 256) {
        su[e]  = gu[b * 2560 + e];
        sw2[e] = W2[e];
    }
    __syncthreads();
    if (tid < 248) {
        int tp = tid >> 3, l8 = tid & 7;
        const float* vrow = V + (b * TM1 + tp) * 512;
        float p = 0.f;
        for (int e = l8; e < 512; e += 8) p += tanh_fast(su[e] + vrow[e]) * sw2[e];
        p += __shfl_xor(p, 1); p += __shfl_xor(p, 2); p += __shfl_xor(p, 4);
        if (l8 == 0) s_att[tp] = p + b2[0];
    }
    __syncthreads();
    if (tid < 64) {
        float v = (tid < TM1) ? s_att[tid] : -3.4e38f;
        float m = v;
#pragma unroll
        for (int k = 32; k > 0; k >>= 1) m = fmaxf(m, __shfl_xor(m, k));
        float e = (tid < TM1) ? __expf(v - m) : 0.f;
        float s = e;
#pragma unroll
        for (int k = 32; k > 0; k >>= 1) s += __shfl_xor(s, k);
        if (tid < TM1) s_att[tid] = e / s;
    }
    __syncthreads();

    // ctx[e] and y_tilde partial
    float part = 0.f;
#pragma unroll
    for (int r = 0; r < 2; r++) {
        int e = tid + r * 256;
        float cx = 0.f;
        const float* ep = enc_out + b * TM1 * 512 + e;
        for (int tp = 0; tp < TM1; tp++) cx += s_att[tp] * ep[tp * 512];
        ctx[b * 512 + e] = cx;
        part += cx * fcW[e];
    }
    float y = inputs[(b * TM1 + t) * 257];
    float ysum = blockReduceSum256(part, sred);
    float y_til = ysum + y * fcW[512] + fcb[0];

    for (int e = tid; e < 512; e += 256) {
        float gi = gu[b * 2560 + 512 + e]        + y_til * Wih[e];
        float gf = gu[b * 2560 + 1024 + e]       + y_til * Wih[512 + e];
        float gg = gu[b * 2560 + 1536 + e]       + y_til * Wih[1024 + e];
        float go = gu[b * 2560 + 2048 + e]       + y_til * Wih[1536 + e];
        float cp = hc[b * 1024 + 512 + e];
        float c2 = sigmf(gf) * cp + sigmf(gi) * tanh_fast(gg);
        float h2 = sigmf(go) * tanh_fast(c2);
        hc[b * 1024 + e] = h2;
        hc[b * 1024 + 512 + e] = c2;
    }
}

// ---------------------------------------------------------------------------
// final: out[b] = [hT | ctxT] . fcfW + fcfb
// ---------------------------------------------------------------------------
__global__ __launch_bounds__(256) void final_kernel(
    const float* __restrict__ hc, const float* __restrict__ ctx,
    const float* __restrict__ fcfW, const float* __restrict__ fcfb,
    float* __restrict__ out) {
    __shared__ float sred[4];
    int b = blockIdx.x, tid = threadIdx.x;
    float p = 0.f;
    for (int e = tid; e < 512; e += 256)
        p += hc[b * 1024 + e] * fcfW[e] + ctx[b * 512 + e] * fcfW[512 + e];
    float s = blockReduceSum256(p, sred);
    if (tid == 0) out[b] = s + fcfb[0];
}

static inline void launch_gemm(const float* A, int lda, const float* W, int ldw,
                               const float* bias, float* C, int ldc,
                               int M, int N, int K, hipStream_t s) {
    dim3 g(N / 64, M / 64);
    hipLaunchKernelGGL(gemm_tn, g, dim3(256), 0, s, A, lda, W, ldw, bias, C, ldc, K);
}

extern "C" void kernel_launch(void* const* d_in, const int* in_sizes, int n_in,
                              void* d_out, int out_size, void* d_ws, size_t ws_size,
                              hipStream_t stream) {
    const float* inputs  = (const float*)d_in[0];
    const float* eWih    = (const float*)d_in[1];
    const float* eWhh    = (const float*)d_in[2];
    const float* ebih    = (const float*)d_in[3];
    const float* ebhh    = (const float*)d_in[4];
    const float* eWc     = (const float*)d_in[5];
    const float* ebc     = (const float*)d_in[6];
    const float* eWd     = (const float*)d_in[7];
    const float* ebd     = (const float*)d_in[8];
    const float* eWa     = (const float*)d_in[9];
    const float* eba     = (const float*)d_in[10];
    const float* dW1     = (const float*)d_in[11];
    const float* db1     = (const float*)d_in[12];
    const float* dW2     = (const float*)d_in[13];
    const float* db2     = (const float*)d_in[14];
    const float* dWih    = (const float*)d_in[15];
    const float* dWhh    = (const float*)d_in[16];
    const float* dbih    = (const float*)d_in[17];
    const float* dbhh    = (const float*)d_in[18];
    const float* fcW     = (const float*)d_in[19];
    const float* fcb     = (const float*)d_in[20];
    const float* fcfW    = (const float*)d_in[21];
    const float* fcfb    = (const float*)d_in[22];
    float* out = (float*)d_out;

    // workspace layout (floats)
    float* ws = (float*)d_ws;
    float* t2s     = ws;                     // 512*31*256  = 4,063,232
    float* A_enc   = t2s     + 4063232;      // 512*768     =   393,216
    float* hc_enc  = A_enc   + 393216;       // 512*1024    =   524,288
    float* g_enc   = hc_enc  + 524288;       // 512*2048    = 1,048,576
    float* enc_out = g_enc   + 1048576;      // 512*31*512  = 8,126,464
    float* V       = enc_out + 8126464;      // 512*31*512  = 8,126,464
    float* hc_dec  = V       + 8126464;      // 512*1024    =   524,288
    float* gu      = hc_dec  + 524288;       // 512*2560    = 1,310,720
    float* ctx     = gu      + 1310720;      // 512*512     =   262,144
    float* eWcomb  = ctx     + 262144;       // 2048*768    = 1,572,864
    float* ebcomb  = eWcomb  + 1572864;      // 2048
    float* dbias   = ebcomb  + 2048;         // 2560
    // total ~ 25.96M floats ~= 104 MB

    hipLaunchKernelGGL(prep_kernel, dim3(512), dim3(256), 0, stream,
                       eWih, eWhh, ebih, ebhh, dbih, dbhh, eWcomb, ebcomb, dbias, hc_dec);
    hipLaunchKernelGGL(t2s_kernel, dim3(BATCH), dim3(256), 0, stream, inputs, eWd, ebd, t2s);

    // -------- encoder --------
    for (int t = 0; t < TM1; t++) {
        hipLaunchKernelGGL(enc_step_kernel, dim3(BATCH), dim3(256), 0, stream,
                           inputs, t2s, eWc, ebc, eWa, eba, g_enc, hc_enc, A_enc, enc_out, t);
        launch_gemm(A_enc, 768, eWcomb, 768, ebcomb, g_enc, 2048, BATCH, 2048, 768, stream);
    }
    // finalize last LSTM step (writes enc_out[:,30,:])
    hipLaunchKernelGGL(enc_step_kernel, dim3(BATCH), dim3(256), 0, stream,
                       inputs, t2s, eWc, ebc, eWa, eba, g_enc, hc_enc, A_enc, enc_out, TM1);

    // -------- V = enc_out @ dec_W1[:,1024:]^T + b1   (M=512*31) --------
    launch_gemm(enc_out, 512, dW1 + 1024, 1536, db1, V, 512, BATCH * TM1, 512, 512, stream);

    // -------- decoder --------
    for (int t = 0; t < TM1; t++) {
        // u = [h|c] @ dec_W1[:, :1024]^T    -> gu[:, 0:512]
        launch_gemm(hc_dec, 1024, dW1, 1536, dbias, gu, 2560, BATCH, 512, 1024, stream);
        // gh = h @ dec_Whh^T + (bih+bhh)    -> gu[:, 512:2560]
        launch_gemm(hc_dec, 1024, dWhh, 512, dbias + 512, gu + 512, 2560, BATCH, 2048, 512, stream);
        hipLaunchKernelGGL(dec_step_kernel, dim3(BATCH), dim3(256), 0, stream,
                           inputs, V, dW2, db2, enc_out, fcW, fcb, dWih, gu, hc_dec, ctx, t);
    }

    hipLaunchKernelGGL(final_kernel, dim3(BATCH), dim3(256), 0, stream,
                       hc_dec, ctx, fcfW, fcfb, out);
}

// Round 2
// 3605.521 us; speedup vs baseline: 1.6975x; 1.6975x over previous
//
#include <hip/hip_runtime.h>
#include <math.h>

#define BATCH 512
#define TM1   31
#define DIMD  256

typedef _Float16 f16;
typedef _Float16 half8 __attribute__((ext_vector_type(8)));
typedef float floatx4 __attribute__((ext_vector_type(4)));

__device__ __forceinline__ float sigmf(float x) { return 1.f / (1.f + __expf(-x)); }

__device__ __forceinline__ float tanh_fast(float x) {
    float ax = fabsf(x);
    float t  = __expf(-2.f * ax);
    float r  = (1.f - t) / (1.f + t);
    return copysignf(r, x);
}

__device__ __forceinline__ void split16(float x, f16* hi, f16* lo) {
    f16 h = (f16)x;
    *hi = h;
    *lo = (f16)(x - (float)h);
}

__device__ __forceinline__ float blockReduceSum256(float v, float* sred) {
#pragma unroll
    for (int m = 32; m > 0; m >>= 1) v += __shfl_xor(v, m);
    __syncthreads();
    if ((threadIdx.x & 63) == 0) sred[threadIdx.x >> 6] = v;
    __syncthreads();
    return sred[0] + sred[1] + sred[2] + sred[3];
}

__device__ __forceinline__ float blockReduceMax256(float v, float* sred) {
#pragma unroll
    for (int m = 32; m > 0; m >>= 1) v = fmaxf(v, __shfl_xor(v, m));
    __syncthreads();
    if ((threadIdx.x & 63) == 0) sred[threadIdx.x >> 6] = v;
    __syncthreads();
    return fmaxf(fmaxf(sred[0], sred[1]), fmaxf(sred[2], sred[3]));
}

// ---------------------------------------------------------------------------
// prep: split weights into fp16 hi/lo pairs; combined biases.
//  eW   : [2048 x 768]  = [enc_Wih | enc_Whh]
//  dWc  : [2560 x 1024] = rows<512: dec_W1[:, :1024]; rows>=512: [dec_Whh | X]
//         (X region k>=512,n>=512 is never read by the GEMM: kend=512 there)
//  Vw   : [512 x 512]   = dec_W1[:, 1024:]
// ---------------------------------------------------------------------------
__global__ __launch_bounds__(256) void prep_kernel(
    const float* __restrict__ eWih, const float* __restrict__ eWhh,
    const float* __restrict__ ebih, const float* __restrict__ ebhh,
    const float* __restrict__ dW1,  const float* __restrict__ dWhh,
    const float* __restrict__ dbih, const float* __restrict__ dbhh,
    f16* __restrict__ eWhi, f16* __restrict__ eWlo,
    f16* __restrict__ dWchi, f16* __restrict__ dWclo,
    f16* __restrict__ Vwhi, f16* __restrict__ Vwlo,
    float* __restrict__ ebcomb, float* __restrict__ dbias)
{
    int idx = blockIdx.x * blockDim.x + threadIdx.x;
    int stride = gridDim.x * blockDim.x;
    for (int i = idx; i < 2048 * 768; i += stride) {
        int n = i / 768, k = i - n * 768;
        float v = (k < 256) ? eWih[n * 256 + k] : eWhh[n * 512 + (k - 256)];
        split16(v, &eWhi[i], &eWlo[i]);
    }
    for (int i = idx; i < 2560 * 1024; i += stride) {
        int n = i >> 10, k = i & 1023;
        float v;
        if (n < 512)      v = dW1[n * 1536 + k];
        else if (k < 512) v = dWhh[(n - 512) * 512 + k];
        else              v = 0.f;
        split16(v, &dWchi[i], &dWclo[i]);
    }
    for (int i = idx; i < 512 * 512; i += stride) {
        int n = i >> 9, k = i & 511;
        split16(dW1[n * 1536 + 1024 + k], &Vwhi[i], &Vwlo[i]);
    }
    for (int i = idx; i < 2048; i += stride) ebcomb[i] = ebih[i] + ebhh[i];
    for (int i = idx; i < 2560; i += stride)
        dbias[i] = (i < 512) ? 0.f : (dbih[i - 512] + dbhh[i - 512]);
}

// ---------------------------------------------------------------------------
// t2s[b][s][d] = sum_t X[b,t,d]*Wd[s,t] + bd[s]
// ---------------------------------------------------------------------------
__global__ __launch_bounds__(256) void t2s_kernel(
    const float* __restrict__ inputs, const float* __restrict__ Wd,
    const float* __restrict__ bd, float* __restrict__ t2s) {
    __shared__ float sX[TM1 * DIMD];
    __shared__ float sWd[TM1 * TM1];
    int b = blockIdx.x, tid = threadIdx.x;
    for (int i = tid; i < TM1 * DIMD; i += 256) {
        int tt = i >> 8, d = i & 255;
        sX[i] = inputs[(b * TM1 + tt) * 257 + 1 + d];
    }
    for (int i = tid; i < TM1 * TM1; i += 256) sWd[i] = Wd[i];
    __syncthreads();
    int d = tid;
    for (int s = 0; s < TM1; s++) {
        float acc = bd[s];
        for (int tt = 0; tt < TM1; tt++) acc += sX[tt * DIMD + d] * sWd[s * TM1 + tt];
        t2s[(b * TM1 + s) * DIMD + d] = acc;
    }
}

// ---------------------------------------------------------------------------
// fp16x3 MFMA GEMM: C[m,n] = sum_k A[m,k]*W[n,k] + bias[n]
// A,W given as hi/lo fp16 pairs; 3 passes (Ahi*Whi + Ahi*Wlo + Alo*Whi)
// gives ~fp32 accuracy. 64x64 block tile, 4 waves of 32x32, BK=64 LDS
// staging (stride 72 halves -> 2-way-only bank aliasing, free).
// kend = (n0 >= nsplit) ? 512 : K  (decoder Whh half needs only h, k<512).
// ---------------------------------------------------------------------------
__global__ __launch_bounds__(256) void gemm3_f16(
    const f16* __restrict__ Ahi, const f16* __restrict__ Alo, int lda,
    const f16* __restrict__ Whi, const f16* __restrict__ Wlo, int ldw,
    const float* __restrict__ bias, float* __restrict__ C, int ldc,
    int K, int nsplit)
{
    __shared__ __align__(16) f16 As[64][72];
    __shared__ __align__(16) f16 Ws[64][72];
    int tid = threadIdx.x;
    int n0 = blockIdx.x * 64;
    int m0 = blockIdx.y * 64;
    int kend = (n0 >= nsplit) ? 512 : K;
    int wid = tid >> 6, lane = tid & 63;
    int l15 = lane & 15, quad = lane >> 4;
    int wm = wid >> 1, wn = wid & 1;
    int srow = tid >> 2;
    int scol = (tid & 3) << 4;
    floatx4 acc[2][2] = {};
    for (int pass = 0; pass < 3; ++pass) {
        const f16* Ap = (pass == 2) ? Alo : Ahi;
        const f16* Wp = (pass == 1) ? Wlo : Whi;
        const f16* Ag = Ap + (size_t)(m0 + srow) * lda + scol;
        const f16* Wg = Wp + (size_t)(n0 + srow) * ldw + scol;
        for (int k0 = 0; k0 < kend; k0 += 64) {
            float4 av0 = *(const float4*)(Ag + k0);
            float4 av1 = *(const float4*)(Ag + k0 + 8);
            float4 wv0 = *(const float4*)(Wg + k0);
            float4 wv1 = *(const float4*)(Wg + k0 + 8);
            __syncthreads();
            *(float4*)(&As[srow][scol])     = av0;
            *(float4*)(&As[srow][scol + 8]) = av1;
            *(float4*)(&Ws[srow][scol])     = wv0;
            *(float4*)(&Ws[srow][scol + 8]) = wv1;
            __syncthreads();
#pragma unroll
            for (int ks = 0; ks < 64; ks += 32) {
                half8 a0 = *(const half8*)(&As[wm * 32 + l15][ks + quad * 8]);
                half8 a1 = *(const half8*)(&As[wm * 32 + 16 + l15][ks + quad * 8]);
                half8 b0 = *(const half8*)(&Ws[wn * 32 + l15][ks + quad * 8]);
                half8 b1 = *(const half8*)(&Ws[wn * 32 + 16 + l15][ks + quad * 8]);
                acc[0][0] = __builtin_amdgcn_mfma_f32_16x16x32_f16(a0, b0, acc[0][0], 0, 0, 0);
                acc[0][1] = __builtin_amdgcn_mfma_f32_16x16x32_f16(a0, b1, acc[0][1], 0, 0, 0);
                acc[1][0] = __builtin_amdgcn_mfma_f32_16x16x32_f16(a1, b0, acc[1][0], 0, 0, 0);
                acc[1][1] = __builtin_amdgcn_mfma_f32_16x16x32_f16(a1, b1, acc[1][1], 0, 0, 0);
            }
        }
    }
#pragma unroll
    for (int mi = 0; mi < 2; ++mi)
#pragma unroll
        for (int ni = 0; ni < 2; ++ni) {
            int col = n0 + wn * 32 + ni * 16 + l15;
            float bv = bias[col];
#pragma unroll
            for (int r = 0; r < 4; ++r) {
                int row = m0 + wm * 32 + mi * 16 + quad * 4 + r;
                C[(size_t)row * ldc + col] = acc[mi][ni][r] + bv;
            }
        }
}

// ---------------------------------------------------------------------------
// Encoder step: finalize LSTM of step t-1 (from g), then attention for step t.
// Writes A = [w | h] as fp16 hi/lo for the MFMA GEMM, and enc_h as hi/lo.
// t==31: finalize only + zero decoder h/c state.
// ---------------------------------------------------------------------------
__global__ __launch_bounds__(256) void enc_step_kernel(
    const float* __restrict__ inputs, const float* __restrict__ t2s,
    const float* __restrict__ Wc, const float* __restrict__ bc,
    const float* __restrict__ Wa, const float* __restrict__ ba,
    const float* __restrict__ g, float* __restrict__ hc,
    f16* __restrict__ Ahi, f16* __restrict__ Alo,
    f16* __restrict__ enchi, f16* __restrict__ enclo,
    float* __restrict__ hc_dec, f16* __restrict__ hdhi, f16* __restrict__ hdlo,
    int t) {
    __shared__ float sh_hc[1024];
    __shared__ float t1s[TM1];
    __shared__ float sred[4];
    int b = blockIdx.x, tid = threadIdx.x;
    if (t > 0) {
        for (int e = tid; e < 512; e += 256) {
            float gi = g[b * 2048 + e];
            float gf = g[b * 2048 + 512 + e];
            float gg = g[b * 2048 + 1024 + e];
            float go = g[b * 2048 + 1536 + e];
            float cp = hc[b * 1024 + 512 + e];
            float c2 = sigmf(gf) * cp + sigmf(gi) * tanh_fast(gg);
            float h2 = sigmf(go) * tanh_fast(c2);
            hc[b * 1024 + e] = h2;
            hc[b * 1024 + 512 + e] = c2;
            sh_hc[e] = h2;
            sh_hc[512 + e] = c2;
            split16(h2, &enchi[(b * TM1 + (t - 1)) * 512 + e],
                        &enclo[(b * TM1 + (t - 1)) * 512 + e]);
        }
    } else {
        for (int j = tid; j < 1024; j += 256) { sh_hc[j] = 0.f; hc[b * 1024 + j] = 0.f; }
    }
    if (t == TM1) {
        // final encoder call: also zero decoder state
        for (int j = tid; j < 1024; j += 256) {
            hc_dec[b * 1024 + j] = 0.f;
            hdhi[b * 1024 + j] = (f16)0.f;
            hdlo[b * 1024 + j] = (f16)0.f;
        }
        return;
    }
    __syncthreads();

    if (tid < 248) {
        int s = tid >> 3, l8 = tid & 7;
        const float* wrow = Wc + s * 1024;
        float p = 0.f;
        for (int j = l8; j < 1024; j += 8) p += sh_hc[j] * wrow[j];
        p += __shfl_xor(p, 1); p += __shfl_xor(p, 2); p += __shfl_xor(p, 4);
        if (l8 == 0) t1s[s] = p + bc[s];
    }
    __syncthreads();

    int d = tid;
    float sc = ba[0];
    const float* t2p = t2s + b * TM1 * DIMD + d;
    for (int s = 0; s < TM1; s++) sc += tanh_fast(t1s[s] + t2p[s * DIMD]) * Wa[s];
    float mx = blockReduceMax256(sc, sred);
    float ex = __expf(sc - mx);
    float sm = blockReduceSum256(ex, sred);
    float w = (ex / sm) * inputs[(b * TM1 + t) * 257 + 1 + d];
    split16(w, &Ahi[b * 768 + d], &Alo[b * 768 + d]);
    for (int j = tid; j < 512; j += 256)
        split16(sh_hc[j], &Ahi[b * 768 + 256 + j], &Alo[b * 768 + 256 + j]);
}

// ---------------------------------------------------------------------------
// Decoder step: temporal attention + ctx + y_tilde + LSTM pointwise.
// ---------------------------------------------------------------------------
__global__ __launch_bounds__(256) void dec_step_kernel(
    const float* __restrict__ inputs, const float* __restrict__ V,
    const float* __restrict__ W2, const float* __restrict__ b2,
    const f16* __restrict__ enchi, const f16* __restrict__ enclo,
    const float* __restrict__ fcW, const float* __restrict__ fcb,
    const float* __restrict__ Wih, const float* __restrict__ gu,
    float* __restrict__ hc, f16* __restrict__ hdhi, f16* __restrict__ hdlo,
    float* __restrict__ ctx, int t) {
    __shared__ float su[512];
    __shared__ float sw2[512];
    __shared__ float s_att[TM1];
    __shared__ float sred[4];
    int b = blockIdx.x, tid = threadIdx.x;
    for (int e = tid; e < 512; e += 256) {
        su[e]  = gu[b * 2560 + e];
        sw2[e] = W2[e];
    }
    __syncthreads();
    if (tid < 248) {
        int tp = tid >> 3, l8 = tid & 7;
        const float* vrow = V + (b * TM1 + tp) * 512;
        float p = 0.f;
        for (int e = l8; e < 512; e += 8) p += tanh_fast(su[e] + vrow[e]) * sw2[e];
        p += __shfl_xor(p, 1); p += __shfl_xor(p, 2); p += __shfl_xor(p, 4);
        if (l8 == 0) s_att[tp] = p + b2[0];
    }
    __syncthreads();
    if (tid < 64) {
        float v = (tid < TM1) ? s_att[tid] : -3.4e38f;
        float m = v;
#pragma unroll
        for (int k = 32; k > 0; k >>= 1) m = fmaxf(m, __shfl_xor(m, k));
        float e = (tid < TM1) ? __expf(v - m) : 0.f;
        float s = e;
#pragma unroll
        for (int k = 32; k > 0; k >>= 1) s += __shfl_xor(s, k);
        if (tid < TM1) s_att[tid] = e / s;
    }
    __syncthreads();

    float part = 0.f;
#pragma unroll
    for (int r = 0; r < 2; r++) {
        int e = tid + r * 256;
        float cx = 0.f;
        const f16* eh = enchi + (size_t)b * TM1 * 512 + e;
        const f16* el = enclo + (size_t)b * TM1 * 512 + e;
        for (int tp = 0; tp < TM1; tp++)
            cx += s_att[tp] * ((float)eh[tp * 512] + (float)el[tp * 512]);
        ctx[b * 512 + e] = cx;
        part += cx * fcW[e];
    }
    float y = inputs[(b * TM1 + t) * 257];
    float ysum = blockReduceSum256(part, sred);
    float y_til = ysum + y * fcW[512] + fcb[0];

    for (int e = tid; e < 512; e += 256) {
        float gi = gu[b * 2560 + 512 + e]  + y_til * Wih[e];
        float gf = gu[b * 2560 + 1024 + e] + y_til * Wih[512 + e];
        float gg = gu[b * 2560 + 1536 + e] + y_til * Wih[1024 + e];
        float go = gu[b * 2560 + 2048 + e] + y_til * Wih[1536 + e];
        float cp = hc[b * 1024 + 512 + e];
        float c2 = sigmf(gf) * cp + sigmf(gi) * tanh_fast(gg);
        float h2 = sigmf(go) * tanh_fast(c2);
        hc[b * 1024 + e] = h2;
        hc[b * 1024 + 512 + e] = c2;
        split16(h2, &hdhi[b * 1024 + e], &hdlo[b * 1024 + e]);
        split16(c2, &hdhi[b * 1024 + 512 + e], &hdlo[b * 1024 + 512 + e]);
    }
}

__global__ __launch_bounds__(256) void final_kernel(
    const float* __restrict__ hc, const float* __restrict__ ctx,
    const float* __restrict__ fcfW, const float* __restrict__ fcfb,
    float* __restrict__ out) {
    __shared__ float sred[4];
    int b = blockIdx.x, tid = threadIdx.x;
    float p = 0.f;
    for (int e = tid; e < 512; e += 256)
        p += hc[b * 1024 + e] * fcfW[e] + ctx[b * 512 + e] * fcfW[512 + e];
    float s = blockReduceSum256(p, sred);
    if (tid == 0) out[b] = s + fcfb[0];
}

extern "C" void kernel_launch(void* const* d_in, const int* in_sizes, int n_in,
                              void* d_out, int out_size, void* d_ws, size_t ws_size,
                              hipStream_t stream) {
    const float* inputs  = (const float*)d_in[0];
    const float* eWih    = (const float*)d_in[1];
    const float* eWhh    = (const float*)d_in[2];
    const float* ebih    = (const float*)d_in[3];
    const float* ebhh    = (const float*)d_in[4];
    const float* eWc     = (const float*)d_in[5];
    const float* ebc     = (const float*)d_in[6];
    const float* eWd     = (const float*)d_in[7];
    const float* ebd     = (const float*)d_in[8];
    const float* eWa     = (const float*)d_in[9];
    const float* eba     = (const float*)d_in[10];
    const float* dW1     = (const float*)d_in[11];
    const float* db1     = (const float*)d_in[12];
    const float* dW2     = (const float*)d_in[13];
    const float* db2     = (const float*)d_in[14];
    const float* dWih    = (const float*)d_in[15];
    const float* dWhh    = (const float*)d_in[16];
    const float* dbih    = (const float*)d_in[17];
    const float* dbhh    = (const float*)d_in[18];
    const float* fcW     = (const float*)d_in[19];
    const float* fcb     = (const float*)d_in[20];
    const float* fcfW    = (const float*)d_in[21];
    const float* fcfb    = (const float*)d_in[22];
    float* out = (float*)d_out;

    // -------- workspace layout (phase-overlapped; 23,335,424 floats ~= 93 MB)
    float* scr = (float*)d_ws;
    // encoder-phase view of scratch
    float* t2s    = scr;                        // 4,063,232 f
    float* g_enc  = scr + 4063232;              // 1,048,576 f
    float* hc_enc = scr + 5111808;              //   524,288 f
    f16*   Ahi    = (f16*)(scr + 5636096);      //   393,216 h
    f16*   Alo    = Ahi + 393216;               //   393,216 h
    // decoder-phase view of scratch (encoder arrays dead by then)
    float* V      = scr;                        // 8,126,464 f
    float* gu     = scr + 8126464;              // 1,310,720 f
    float* ctx    = scr + 9437184;              //   262,144 f
    float* hc_dec = scr + 9699328;              //   524,288 f
    f16*   hdhi   = (f16*)(scr + 10223616);     //   524,288 h
    f16*   hdlo   = hdhi + 524288;              //   524,288 h
    // persistent
    float* pers   = scr + 10747904;
    f16* eWhi  = (f16*)pers;                    // 1,572,864 h
    f16* eWlo  = eWhi + 1572864;
    f16* dWchi = eWlo + 1572864;                // 2,621,440 h
    f16* dWclo = dWchi + 2621440;
    f16* Vwhi  = dWclo + 2621440;               //   262,144 h
    f16* Vwlo  = Vwhi + 262144;
    f16* enchi = Vwlo + 262144;                 // 8,126,464 h
    f16* enclo = enchi + 8126464;
    float* ebcomb = (float*)(enclo + 8126464);  // 2048 f
    float* dbias  = ebcomb + 2048;              // 2560 f

    hipLaunchKernelGGL(prep_kernel, dim3(512), dim3(256), 0, stream,
                       eWih, eWhh, ebih, ebhh, dW1, dWhh, dbih, dbhh,
                       eWhi, eWlo, dWchi, dWclo, Vwhi, Vwlo, ebcomb, dbias);
    hipLaunchKernelGGL(t2s_kernel, dim3(BATCH), dim3(256), 0, stream, inputs, eWd, ebd, t2s);

    // -------- encoder --------
    for (int t = 0; t < TM1; t++) {
        hipLaunchKernelGGL(enc_step_kernel, dim3(BATCH), dim3(256), 0, stream,
                           inputs, t2s, eWc, ebc, eWa, eba, g_enc, hc_enc,
                           Ahi, Alo, enchi, enclo, hc_dec, hdhi, hdlo, t);
        hipLaunchKernelGGL(gemm3_f16, dim3(32, 8), dim3(256), 0, stream,
                           Ahi, Alo, 768, eWhi, eWlo, 768, ebcomb,
                           g_enc, 2048, 768, 1 << 30);
    }
    // finalize last LSTM step (writes enc row 30) + zero decoder state
    hipLaunchKernelGGL(enc_step_kernel, dim3(BATCH), dim3(256), 0, stream,
                       inputs, t2s, eWc, ebc, eWa, eba, g_enc, hc_enc,
                       Ahi, Alo, enchi, enclo, hc_dec, hdhi, hdlo, TM1);

    // -------- V = enc_out @ dec_W1[:,1024:]^T + b1 --------
    hipLaunchKernelGGL(gemm3_f16, dim3(8, 248), dim3(256), 0, stream,
                       enchi, enclo, 512, Vwhi, Vwlo, 512, db1,
                       V, 512, 512, 1 << 30);

    // -------- decoder --------
    for (int t = 0; t < TM1; t++) {
        // fused: cols 0..511 = [h|c]@dW1[:, :1024]^T ; cols 512..2559 = h@Whh^T + b
        hipLaunchKernelGGL(gemm3_f16, dim3(40, 8), dim3(256), 0, stream,
                           hdhi, hdlo, 1024, dWchi, dWclo, 1024, dbias,
                           gu, 2560, 1024, 512);
        hipLaunchKernelGGL(dec_step_kernel, dim3(BATCH), dim3(256), 0, stream,
                           inputs, V, dW2, db2, enchi, enclo, fcW, fcb, dWih,
                           gu, hc_dec, hdhi, hdlo, ctx, t);
    }

    hipLaunchKernelGGL(final_kernel, dim3(BATCH), dim3(256), 0, stream,
                       hc_dec, ctx, fcfW, fcfb, out);
}

// Round 3
// 3507.547 us; speedup vs baseline: 1.7450x; 1.0279x over previous
//
#include <hip/hip_runtime.h>
#include <math.h>

#define BATCH 512
#define TM1   31
#define DIMD  256

typedef _Float16 f16;
typedef _Float16 half8 __attribute__((ext_vector_type(8)));
typedef float floatx16 __attribute__((ext_vector_type(16)));

__device__ __forceinline__ float sigmf(float x) { return 1.f / (1.f + __expf(-x)); }

__device__ __forceinline__ float tanh_fast(float x) {
    float ax = fabsf(x);
    float t  = __expf(-2.f * ax);
    float r  = (1.f - t) / (1.f + t);
    return copysignf(r, x);
}

__device__ __forceinline__ void split16(float x, f16* hi, f16* lo) {
    f16 h = (f16)x;
    *hi = h;
    *lo = (f16)(x - (float)h);
}

__device__ __forceinline__ float blockReduceSum256(float v, float* sred) {
#pragma unroll
    for (int m = 32; m > 0; m >>= 1) v += __shfl_xor(v, m);
    __syncthreads();
    if ((threadIdx.x & 63) == 0) sred[threadIdx.x >> 6] = v;
    __syncthreads();
    return sred[0] + sred[1] + sred[2] + sred[3];
}

// ---------------------------------------------------------------------------
// prep: split weights into fp16 hi/lo pairs; combined biases.
// ---------------------------------------------------------------------------
__global__ __launch_bounds__(256) void prep_kernel(
    const float* __restrict__ eWih, const float* __restrict__ eWhh,
    const float* __restrict__ ebih, const float* __restrict__ ebhh,
    const float* __restrict__ dW1,  const float* __restrict__ dWhh,
    const float* __restrict__ dbih, const float* __restrict__ dbhh,
    f16* __restrict__ eWhi, f16* __restrict__ eWlo,
    f16* __restrict__ dWchi, f16* __restrict__ dWclo,
    f16* __restrict__ Vwhi, f16* __restrict__ Vwlo,
    float* __restrict__ ebcomb, float* __restrict__ dbias)
{
    int idx = blockIdx.x * blockDim.x + threadIdx.x;
    int stride = gridDim.x * blockDim.x;
    for (int i = idx; i < 2048 * 768; i += stride) {
        int n = i / 768, k = i - n * 768;
        float v = (k < 256) ? eWih[n * 256 + k] : eWhh[n * 512 + (k - 256)];
        split16(v, &eWhi[i], &eWlo[i]);
    }
    for (int i = idx; i < 2560 * 1024; i += stride) {
        int n = i >> 10, k = i & 1023;
        float v;
        if (n < 512)      v = dW1[n * 1536 + k];
        else if (k < 512) v = dWhh[(n - 512) * 512 + k];
        else              v = 0.f;
        split16(v, &dWchi[i], &dWclo[i]);
    }
    for (int i = idx; i < 512 * 512; i += stride) {
        int n = i >> 9, k = i & 511;
        split16(dW1[n * 1536 + 1024 + k], &Vwhi[i], &Vwlo[i]);
    }
    for (int i = idx; i < 2048; i += stride) ebcomb[i] = ebih[i] + ebhh[i];
    for (int i = idx; i < 2560; i += stride)
        dbias[i] = (i < 512) ? 0.f : (dbih[i - 512] + dbhh[i - 512]);
}

// ---------------------------------------------------------------------------
// t2s[b][s][d] = sum_t X[b,t,d]*Wd[s,t] + bd[s]
// ---------------------------------------------------------------------------
__global__ __launch_bounds__(256) void t2s_kernel(
    const float* __restrict__ inputs, const float* __restrict__ Wd,
    const float* __restrict__ bd, float* __restrict__ t2s) {
    __shared__ float sX[TM1 * DIMD];
    __shared__ float sWd[TM1 * TM1];
    int b = blockIdx.x, tid = threadIdx.x;
    for (int i = tid; i < TM1 * DIMD; i += 256) {
        int tt = i >> 8, d = i & 255;
        sX[i] = inputs[(b * TM1 + tt) * 257 + 1 + d];
    }
    for (int i = tid; i < TM1 * TM1; i += 256) sWd[i] = Wd[i];
    __syncthreads();
    int d = tid;
    for (int s = 0; s < TM1; s++) {
        float acc = bd[s];
        for (int tt = 0; tt < TM1; tt++) acc += sX[tt * DIMD + d] * sWd[s * TM1 + tt];
        t2s[(b * TM1 + s) * DIMD + d] = acc;
    }
}

// ---------------------------------------------------------------------------
// fp16x3 fused MFMA GEMM: C[m,n] = sum_k A[m,k]*W[n,k] + bias[n]
// One K-loop computing Ahi*Whi + Ahi*Wlo + Alo*Whi per chunk.
// 64x64 tile, 4 waves of 32x32 (mfma_32x32x16_f16), BK=64.
// LDS XOR-swizzle on 16B granules -> conflict-free b128.
// Register prefetch pipeline overlaps global loads with MFMA.
// kend = (n0 >= nsplit) ? 512 : K.
// ---------------------------------------------------------------------------
__global__ __launch_bounds__(256) void gemm3f(
    const f16* __restrict__ Ahi, const f16* __restrict__ Alo, int lda,
    const f16* __restrict__ Whi, const f16* __restrict__ Wlo, int ldw,
    const float* __restrict__ bias, float* __restrict__ C, int ldc,
    int K, int nsplit)
{
    __shared__ f16 sAh[64 * 64];
    __shared__ f16 sAl[64 * 64];
    __shared__ f16 sWh[64 * 64];
    __shared__ f16 sWl[64 * 64];
    int tid = threadIdx.x;
    int n0 = blockIdx.x * 64, m0 = blockIdx.y * 64;
    int kend = (n0 >= nsplit) ? 512 : K;
    int lane = tid & 63, wid = tid >> 6;
    int wm = wid >> 1, wn = wid & 1;
    int rl = lane & 31, kq = lane >> 5;

    // staging map: thread -> (row, granule pair)
    int sr = tid >> 2;
    int g0 = (tid & 3) * 2;
    const f16* pAh = Ahi + (size_t)(m0 + sr) * lda + g0 * 8;
    const f16* pAl = Alo + (size_t)(m0 + sr) * lda + g0 * 8;
    const f16* pWh = Whi + (size_t)(n0 + sr) * ldw + g0 * 8;
    const f16* pWl = Wlo + (size_t)(n0 + sr) * ldw + g0 * 8;
    int s0 = sr * 64 + ((g0 ^ (sr & 7)) * 8);
    int s1 = sr * 64 + (((g0 + 1) ^ (sr & 7)) * 8);

    float4 rAh0 = *(const float4*)(pAh);
    float4 rAh1 = *(const float4*)(pAh + 8);
    float4 rAl0 = *(const float4*)(pAl);
    float4 rAl1 = *(const float4*)(pAl + 8);
    float4 rWh0 = *(const float4*)(pWh);
    float4 rWh1 = *(const float4*)(pWh + 8);
    float4 rWl0 = *(const float4*)(pWl);
    float4 rWl1 = *(const float4*)(pWl + 8);

    floatx16 acc = {};
    int arow = (wm * 32 + rl) * 64;
    int wrow = (wn * 32 + rl) * 64;
    int sw = (rl & 7);

    for (int k0 = 0; k0 < kend; k0 += 64) {
        __syncthreads();
        *(float4*)&sAh[s0] = rAh0; *(float4*)&sAh[s1] = rAh1;
        *(float4*)&sAl[s0] = rAl0; *(float4*)&sAl[s1] = rAl1;
        *(float4*)&sWh[s0] = rWh0; *(float4*)&sWh[s1] = rWh1;
        *(float4*)&sWl[s0] = rWl0; *(float4*)&sWl[s1] = rWl1;
        __syncthreads();
        int kn = k0 + 64;
        if (kn < kend) {
            rAh0 = *(const float4*)(pAh + kn); rAh1 = *(const float4*)(pAh + kn + 8);
            rAl0 = *(const float4*)(pAl + kn); rAl1 = *(const float4*)(pAl + kn + 8);
            rWh0 = *(const float4*)(pWh + kn); rWh1 = *(const float4*)(pWh + kn + 8);
            rWl0 = *(const float4*)(pWl + kn); rWl1 = *(const float4*)(pWl + kn + 8);
        }
#pragma unroll
        for (int ks = 0; ks < 64; ks += 16) {
            int lg = (ks >> 3) + kq;
            int off = ((lg ^ sw) * 8);
            half8 ah = *(const half8*)&sAh[arow + off];
            half8 al = *(const half8*)&sAl[arow + off];
            half8 wh = *(const half8*)&sWh[wrow + off];
            half8 wl = *(const half8*)&sWl[wrow + off];
            acc = __builtin_amdgcn_mfma_f32_32x32x16_f16(ah, wh, acc, 0, 0, 0);
            acc = __builtin_amdgcn_mfma_f32_32x32x16_f16(ah, wl, acc, 0, 0, 0);
            acc = __builtin_amdgcn_mfma_f32_32x32x16_f16(al, wh, acc, 0, 0, 0);
        }
    }

    int col = n0 + wn * 32 + rl;
    float bv = bias[col];
#pragma unroll
    for (int r = 0; r < 16; ++r) {
        int row = m0 + wm * 32 + (r & 3) + 8 * (r >> 2) + 4 * kq;
        C[(size_t)row * ldc + col] = acc[r] + bv;
    }
}

// ---------------------------------------------------------------------------
// Encoder step: 64 blocks x 8 batch rows. Finalize LSTM t-1, attention t.
// ---------------------------------------------------------------------------
__global__ __launch_bounds__(256) void enc_step_kernel(
    const float* __restrict__ inputs, const float* __restrict__ t2s,
    const float* __restrict__ Wc, const float* __restrict__ bc,
    const float* __restrict__ Wa, const float* __restrict__ ba,
    const float* __restrict__ g, float* __restrict__ hc,
    f16* __restrict__ Ahi, f16* __restrict__ Alo,
    f16* __restrict__ enchi, f16* __restrict__ enclo,
    float* __restrict__ hc_dec, f16* __restrict__ hdhi, f16* __restrict__ hdlo,
    int t) {
    __shared__ float sh[8][1024];   // [h|c] per row
    __shared__ float t1s[8][32];
    int b0 = blockIdx.x * 8, tid = threadIdx.x;

    if (t > 0) {
        for (int e = tid; e < 4096; e += 256) {
            int row = e >> 9, j = e & 511;
            int b = b0 + row;
            float gi = g[b * 2048 + j];
            float gf = g[b * 2048 + 512 + j];
            float gg = g[b * 2048 + 1024 + j];
            float go = g[b * 2048 + 1536 + j];
            float cp = hc[b * 1024 + 512 + j];
            float c2 = sigmf(gf) * cp + sigmf(gi) * tanh_fast(gg);
            float h2 = sigmf(go) * tanh_fast(c2);
            hc[b * 1024 + j] = h2;
            hc[b * 1024 + 512 + j] = c2;
            sh[row][j] = h2;
            sh[row][512 + j] = c2;
            split16(h2, &enchi[((size_t)b * TM1 + (t - 1)) * 512 + j],
                        &enclo[((size_t)b * TM1 + (t - 1)) * 512 + j]);
        }
    } else {
        for (int e = tid; e < 8192; e += 256) {
            int row = e >> 10, j = e & 1023;
            sh[row][j] = 0.f;
            hc[(b0 + row) * 1024 + j] = 0.f;
        }
    }
    if (t == TM1) {
        for (int e = tid; e < 8192; e += 256) {
            int row = e >> 10, j = e & 1023;
            hc_dec[(b0 + row) * 1024 + j] = 0.f;
            hdhi[(b0 + row) * 1024 + j] = (f16)0.f;
            hdlo[(b0 + row) * 1024 + j] = (f16)0.f;
        }
        return;
    }
    __syncthreads();

    int row = tid >> 5, l32 = tid & 31;
    int b = b0 + row;

    // t1[row][s] = [h|c].Wc[s] + bc[s]
    for (int s = 0; s < TM1; s++) {
        const float4* wr = (const float4*)(Wc + s * 1024);
        const float4* hr = (const float4*)(&sh[row][0]);
        float p = 0.f;
        for (int q = l32; q < 256; q += 32) {
            float4 w4 = wr[q], h4 = hr[q];
            p += w4.x * h4.x + w4.y * h4.y + w4.z * h4.z + w4.w * h4.w;
        }
#pragma unroll
        for (int m = 16; m > 0; m >>= 1) p += __shfl_xor(p, m, 32);
        if (l32 == 0) t1s[row][s] = p + bc[s];
    }
    __syncthreads();

    // score + softmax over d (8 d's per lane)
    float sc[8];
#pragma unroll
    for (int k = 0; k < 8; k++) sc[k] = ba[0];
    const float* t2p = t2s + ((size_t)b * TM1) * DIMD;
    for (int s = 0; s < TM1; s++) {
        float t1v = t1s[row][s];
        float wa = Wa[s];
        const float* tp = t2p + s * DIMD;
#pragma unroll
        for (int k = 0; k < 8; k++) sc[k] += tanh_fast(t1v + tp[k * 32 + l32]) * wa;
    }
    float mx = sc[0];
#pragma unroll
    for (int k = 1; k < 8; k++) mx = fmaxf(mx, sc[k]);
#pragma unroll
    for (int m = 16; m > 0; m >>= 1) mx = fmaxf(mx, __shfl_xor(mx, m, 32));
    float sm = 0.f;
#pragma unroll
    for (int k = 0; k < 8; k++) { sc[k] = __expf(sc[k] - mx); sm += sc[k]; }
#pragma unroll
    for (int m = 16; m > 0; m >>= 1) sm += __shfl_xor(sm, m, 32);
    float inv = 1.f / sm;
    const float* xin = inputs + ((size_t)b * TM1 + t) * 257 + 1;
#pragma unroll
    for (int k = 0; k < 8; k++) {
        int d = k * 32 + l32;
        float w = sc[k] * inv * xin[d];
        split16(w, &Ahi[b * 768 + d], &Alo[b * 768 + d]);
    }
    // h columns of A
    for (int e = tid; e < 4096; e += 256) {
        int rr = e >> 9, j = e & 511;
        split16(sh[rr][j], &Ahi[(b0 + rr) * 768 + 256 + j], &Alo[(b0 + rr) * 768 + 256 + j]);
    }
}

// ---------------------------------------------------------------------------
// Decoder step: temporal attention + ctx + y_tilde + LSTM pointwise.
// ---------------------------------------------------------------------------
__global__ __launch_bounds__(256) void dec_step_kernel(
    const float* __restrict__ inputs, const float* __restrict__ V,
    const float* __restrict__ W2, const float* __restrict__ b2,
    const f16* __restrict__ enchi, const f16* __restrict__ enclo,
    const float* __restrict__ fcW, const float* __restrict__ fcb,
    const float* __restrict__ Wih, const float* __restrict__ gu,
    float* __restrict__ hc, f16* __restrict__ hdhi, f16* __restrict__ hdlo,
    float* __restrict__ ctx, int t) {
    __shared__ float su[512];
    __shared__ float sw2[512];
    __shared__ float s_att[TM1];
    __shared__ float sred[4];
    int b = blockIdx.x, tid = threadIdx.x;
    for (int e = tid; e < 512; e += 256) {
        su[e]  = gu[b * 2560 + e];
        sw2[e] = W2[e];
    }
    __syncthreads();
    if (tid < 248) {
        int tp = tid >> 3, l8 = tid & 7;
        const float* vrow = V + ((size_t)b * TM1 + tp) * 512;
        float p = 0.f;
        for (int e = l8; e < 512; e += 8) p += tanh_fast(su[e] + vrow[e]) * sw2[e];
        p += __shfl_xor(p, 1); p += __shfl_xor(p, 2); p += __shfl_xor(p, 4);
        if (l8 == 0) s_att[tp] = p + b2[0];
    }
    __syncthreads();
    if (tid < 64) {
        float v = (tid < TM1) ? s_att[tid] : -3.4e38f;
        float m = v;
#pragma unroll
        for (int k = 32; k > 0; k >>= 1) m = fmaxf(m, __shfl_xor(m, k));
        float e = (tid < TM1) ? __expf(v - m) : 0.f;
        float s = e;
#pragma unroll
        for (int k = 32; k > 0; k >>= 1) s += __shfl_xor(s, k);
        if (tid < TM1) s_att[tid] = e / s;
    }
    __syncthreads();

    float part = 0.f;
#pragma unroll
    for (int r = 0; r < 2; r++) {
        int e = tid + r * 256;
        float cx = 0.f;
        const f16* eh = enchi + (size_t)b * TM1 * 512 + e;
        const f16* el = enclo + (size_t)b * TM1 * 512 + e;
        for (int tp = 0; tp < TM1; tp++)
            cx += s_att[tp] * ((float)eh[tp * 512] + (float)el[tp * 512]);
        ctx[b * 512 + e] = cx;
        part += cx * fcW[e];
    }
    float y = inputs[((size_t)b * TM1 + t) * 257];
    float ysum = blockReduceSum256(part, sred);
    float y_til = ysum + y * fcW[512] + fcb[0];

    for (int e = tid; e < 512; e += 256) {
        float gi = gu[b * 2560 + 512 + e]  + y_til * Wih[e];
        float gf = gu[b * 2560 + 1024 + e] + y_til * Wih[512 + e];
        float gg = gu[b * 2560 + 1536 + e] + y_til * Wih[1024 + e];
        float go = gu[b * 2560 + 2048 + e] + y_til * Wih[1536 + e];
        float cp = hc[b * 1024 + 512 + e];
        float c2 = sigmf(gf) * cp + sigmf(gi) * tanh_fast(gg);
        float h2 = sigmf(go) * tanh_fast(c2);
        hc[b * 1024 + e] = h2;
        hc[b * 1024 + 512 + e] = c2;
        split16(h2, &hdhi[b * 1024 + e], &hdlo[b * 1024 + e]);
        split16(c2, &hdhi[b * 1024 + 512 + e], &hdlo[b * 1024 + 512 + e]);
    }
}

__global__ __launch_bounds__(256) void final_kernel(
    const float* __restrict__ hc, const float* __restrict__ ctx,
    const float* __restrict__ fcfW, const float* __restrict__ fcfb,
    float* __restrict__ out) {
    __shared__ float sred[4];
    int b = blockIdx.x, tid = threadIdx.x;
    float p = 0.f;
    for (int e = tid; e < 512; e += 256)
        p += hc[b * 1024 + e] * fcfW[e] + ctx[b * 512 + e] * fcfW[512 + e];
    float s = blockReduceSum256(p, sred);
    if (tid == 0) out[b] = s + fcfb[0];
}

extern "C" void kernel_launch(void* const* d_in, const int* in_sizes, int n_in,
                              void* d_out, int out_size, void* d_ws, size_t ws_size,
                              hipStream_t stream) {
    const float* inputs  = (const float*)d_in[0];
    const float* eWih    = (const float*)d_in[1];
    const float* eWhh    = (const float*)d_in[2];
    const float* ebih    = (const float*)d_in[3];
    const float* ebhh    = (const float*)d_in[4];
    const float* eWc     = (const float*)d_in[5];
    const float* ebc     = (const float*)d_in[6];
    const float* eWd     = (const float*)d_in[7];
    const float* ebd     = (const float*)d_in[8];
    const float* eWa     = (const float*)d_in[9];
    const float* eba     = (const float*)d_in[10];
    const float* dW1     = (const float*)d_in[11];
    const float* db1     = (const float*)d_in[12];
    const float* dW2     = (const float*)d_in[13];
    const float* db2     = (const float*)d_in[14];
    const float* dWih    = (const float*)d_in[15];
    const float* dWhh    = (const float*)d_in[16];
    const float* dbih    = (const float*)d_in[17];
    const float* dbhh    = (const float*)d_in[18];
    const float* fcW     = (const float*)d_in[19];
    const float* fcb     = (const float*)d_in[20];
    const float* fcfW    = (const float*)d_in[21];
    const float* fcfb    = (const float*)d_in[22];
    float* out = (float*)d_out;

    float* scr = (float*)d_ws;
    // encoder-phase view
    float* t2s    = scr;                        // 4,063,232 f
    float* g_enc  = scr + 4063232;              // 1,048,576 f
    float* hc_enc = scr + 5111808;              //   524,288 f
    f16*   Ahi    = (f16*)(scr + 5636096);      //   393,216 h
    f16*   Alo    = Ahi + 393216;               //   393,216 h
    // decoder-phase view (encoder scratch dead by then)
    float* V      = scr;                        // 8,126,464 f
    float* gu     = scr + 8126464;              // 1,310,720 f
    float* ctx    = scr + 9437184;              //   262,144 f
    float* hc_dec = scr + 9699328;              //   524,288 f
    f16*   hdhi   = (f16*)(scr + 10223616);     //   524,288 h
    f16*   hdlo   = hdhi + 524288;              //   524,288 h
    // persistent
    float* pers   = scr + 10747904;
    f16* eWhi  = (f16*)pers;                    // 1,572,864 h
    f16* eWlo  = eWhi + 1572864;
    f16* dWchi = eWlo + 1572864;                // 2,621,440 h
    f16* dWclo = dWchi + 2621440;
    f16* Vwhi  = dWclo + 2621440;               //   262,144 h
    f16* Vwlo  = Vwhi + 262144;
    f16* enchi = Vwlo + 262144;                 // 8,126,464 h
    f16* enclo = enchi + 8126464;
    float* ebcomb = (float*)(enclo + 8126464);  // 2048 f
    float* dbias  = ebcomb + 2048;              // 2560 f

    hipLaunchKernelGGL(prep_kernel, dim3(512), dim3(256), 0, stream,
                       eWih, eWhh, ebih, ebhh, dW1, dWhh, dbih, dbhh,
                       eWhi, eWlo, dWchi, dWclo, Vwhi, Vwlo, ebcomb, dbias);
    hipLaunchKernelGGL(t2s_kernel, dim3(BATCH), dim3(256), 0, stream, inputs, eWd, ebd, t2s);

    // -------- encoder --------
    for (int t = 0; t < TM1; t++) {
        hipLaunchKernelGGL(enc_step_kernel, dim3(64), dim3(256), 0, stream,
                           inputs, t2s, eWc, ebc, eWa, eba, g_enc, hc_enc,
                           Ahi, Alo, enchi, enclo, hc_dec, hdhi, hdlo, t);
        hipLaunchKernelGGL(gemm3f, dim3(32, 8), dim3(256), 0, stream,
                           Ahi, Alo, 768, eWhi, eWlo, 768, ebcomb,
                           g_enc, 2048, 768, 1 << 30);
    }
    hipLaunchKernelGGL(enc_step_kernel, dim3(64), dim3(256), 0, stream,
                       inputs, t2s, eWc, ebc, eWa, eba, g_enc, hc_enc,
                       Ahi, Alo, enchi, enclo, hc_dec, hdhi, hdlo, TM1);

    // -------- V = enc_out @ dec_W1[:,1024:]^T + b1 --------
    hipLaunchKernelGGL(gemm3f, dim3(8, 248), dim3(256), 0, stream,
                       enchi, enclo, 512, Vwhi, Vwlo, 512, db1,
                       V, 512, 512, 1 << 30);

    // -------- decoder --------
    for (int t = 0; t < TM1; t++) {
        hipLaunchKernelGGL(gemm3f, dim3(40, 8), dim3(256), 0, stream,
                           hdhi, hdlo, 1024, dWchi, dWclo, 1024, dbias,
                           gu, 2560, 1024, 512);
        hipLaunchKernelGGL(dec_step_kernel, dim3(BATCH), dim3(256), 0, stream,
                           inputs, V, dW2, db2, enchi, enclo, fcW, fcb, dWih,
                           gu, hc_dec, hdhi, hdlo, ctx, t);
    }

    hipLaunchKernelGGL(final_kernel, dim3(BATCH), dim3(256), 0, stream,
                       hc_dec, ctx, fcfW, fcfb, out);
}